// Round 9
// baseline (216.759 us; speedup 1.0000x reference)
//
#include <hip/hip_runtime.h>
#include <hip/hip_bf16.h>

// Problem constants
#define B_  2
#define N_  2048
#define D_  1024
#define H_  16
#define DH_ 64
#define BN_ (B_*N_)   // 4096 rows total

typedef __attribute__((ext_vector_type(8))) short short8;    // 8 bf16 (K=16/32 A/B frag)
typedef __attribute__((ext_vector_type(4))) short short4v;   // 4 bf16 (K=8 A/B frag)
typedef __attribute__((ext_vector_type(4))) float f32x4;     // 16x16 C/D frag
typedef __attribute__((ext_vector_type(16))) float f32x16;   // 32x32 C/D frag

typedef __attribute__((address_space(3))) unsigned int lds_u32_t;
typedef const __attribute__((address_space(1))) unsigned int glb_u32_t;

// async global->LDS, 16B per lane; LDS dst = (wave-uniform base) + lane*16
__device__ __forceinline__ void async_load16(const unsigned short* g, unsigned short* l) {
    __builtin_amdgcn_global_load_lds((glb_u32_t*)g, (lds_u32_t*)l, 16, 0, 0);
}

__device__ __forceinline__ unsigned short f2bf(float f) {
    __hip_bfloat16 h = __float2bfloat16(f);
    return *reinterpret_cast<unsigned short*>(&h);
}

// pack bf16(a) low16 | bf16(b) high16; round-half-up + one v_perm_b32
__device__ __forceinline__ unsigned int pkbf(float a, float b) {
    unsigned int ua = __float_as_uint(a) + 0x8000u;
    unsigned int ub = __float_as_uint(b) + 0x8000u;
    return __builtin_amdgcn_perm(ub, ua, 0x07060302);
}

#if __has_builtin(__builtin_amdgcn_exp2f)
#define EXP2(x) __builtin_amdgcn_exp2f(x)
#else
#define EXP2(x) exp2f(x)
#endif

// softmax scale folded into Q projection: 1/sqrt(DH) * log2(e)
#define QSCL 0.1803368801111204f

// ---------------------------------------------------------------------------
// Kernel 1: cast fp32 -> bf16 for x, Wq, Wk, Wv, Wo (one fused launch)
// ---------------------------------------------------------------------------
__global__ __launch_bounds__(256) void cast_kernel(
    const float* __restrict__ x,  const float* __restrict__ wq,
    const float* __restrict__ wk, const float* __restrict__ wv,
    const float* __restrict__ wo,
    unsigned short* __restrict__ xb,  unsigned short* __restrict__ wqb,
    unsigned short* __restrict__ wkb, unsigned short* __restrict__ wvb,
    unsigned short* __restrict__ wob)
{
    const size_t NX = (size_t)BN_ * D_;   // 4194304
    const size_t NW = (size_t)D_ * D_;    // 1048576 (pow2)
    size_t i = ((size_t)blockIdx.x * 256 + threadIdx.x) * 4;
    const float* src; unsigned short* dst; size_t off;
    if (i < NX) { src = x; dst = xb; off = i; }
    else {
        size_t j = (i - NX) >> 20;          // which W
        off = (i - NX) & (NW - 1);
        src = (j == 0) ? wq : (j == 1) ? wk : (j == 2) ? wv : wo;
        dst = (j == 0) ? wqb : (j == 1) ? wkb : (j == 2) ? wvb : wob;
    }
    float4 v = *(const float4*)(src + off);
    ushort4 o;
    o.x = f2bf(v.x); o.y = f2bf(v.y); o.z = f2bf(v.z); o.w = f2bf(v.w);
    *(ushort4*)(dst + off) = o;
}

// ---------------------------------------------------------------------------
// GEMM body: C[M,Nc] = A[M,K](bf16) @ W[Nc,K]^T(bf16) + bias
// LDS buffers passed in (declared once at kernel scope — R8 fix).
// ---------------------------------------------------------------------------
template<int OUT_MODE>
__device__ __forceinline__ void gemm_body(
    unsigned short* __restrict__ As, unsigned short* __restrict__ Bs,
    const unsigned short* __restrict__ A, const unsigned short* __restrict__ W,
    const float* __restrict__ bias, void* __restrict__ Cout, int bx, int by)
{
    constexpr int K = D_;
    const int tid  = threadIdx.x;
    const int lane = tid & 63;
    const int wave = tid >> 6;
    const int wm = wave & 1, wn = wave >> 1;
    const int l15 = lane & 15, quad = lane >> 4;

    f32x4 acc[4][4] = {};
    const int row0 = by * 128, col0 = bx * 128;

    const int srow = lane >> 3;   // row within 1KB chunk (8 rows x 128B)
    const int scb  = lane & 7;    // 16B block within row

    for (int k0 = 0; k0 < K; k0 += 64) {
        __syncthreads();
#pragma unroll
        for (int cc = 0; cc < 4; ++cc) {       // 16 chunks / 4 waves
            int c  = wave * 4 + cc;
            int lr = c * 8 + srow;             // tile row 0..127
            int gcol = k0 + ((scb ^ (lr & 7)) * 8);
            async_load16(A + (size_t)(row0 + lr) * K + gcol, As + c * 512);
            async_load16(W + (size_t)(col0 + lr) * K + gcol, Bs + c * 512);
        }
        __syncthreads();

#pragma unroll
        for (int kf = 0; kf < 2; ++kf) {
            const int swz = ((kf * 4 + quad) ^ (l15 & 7)) * 8;
            short8 af[4], bf[4];
#pragma unroll
            for (int mi = 0; mi < 4; mi++)
                af[mi] = *(const short8*)(&As[(wm * 64 + mi * 16 + l15) * 64 + swz]);
#pragma unroll
            for (int ni = 0; ni < 4; ni++)
                bf[ni] = *(const short8*)(&Bs[(wn * 64 + ni * 16 + l15) * 64 + swz]);
#pragma unroll
            for (int mi = 0; mi < 4; mi++)
#pragma unroll
                for (int ni = 0; ni < 4; ni++)
                    acc[mi][ni] = __builtin_amdgcn_mfma_f32_16x16x32_bf16(
                        af[mi], bf[ni], acc[mi][ni], 0, 0, 0);
        }
    }

#pragma unroll
    for (int ni = 0; ni < 4; ni++) {
        int col = col0 + wn * 64 + ni * 16 + l15;
        float bv = bias[col];
#pragma unroll
        for (int mi = 0; mi < 4; mi++) {
            int row = row0 + wm * 64 + mi * 16 + quad * 4;
            if (OUT_MODE == 2) {
                ushort4 pk;
                pk.x = f2bf(acc[mi][ni][0] + bv);
                pk.y = f2bf(acc[mi][ni][1] + bv);
                pk.z = f2bf(acc[mi][ni][2] + bv);
                pk.w = f2bf(acc[mi][ni][3] + bv);
                *(ushort4*)((unsigned short*)Cout + (size_t)col * BN_ + row) = pk;
            } else {
#pragma unroll
                for (int r = 0; r < 4; r++) {
                    float v = acc[mi][ni][r] + bv;
                    if (OUT_MODE == 3) v *= QSCL;
                    if (OUT_MODE == 0)
                        ((float*)Cout)[(size_t)(row + r) * D_ + col] = v;
                    else
                        ((unsigned short*)Cout)[(size_t)(row + r) * D_ + col] = f2bf(v);
                }
            }
        }
    }
}

// Kernel 2: fused QKV projection (z selects q/k/v; q pre-scaled, v transposed)
__global__ __launch_bounds__(256) void qkv_gemm(
    const unsigned short* __restrict__ xb,
    const unsigned short* __restrict__ wqb, const unsigned short* __restrict__ wkb,
    const unsigned short* __restrict__ wvb,
    const float* __restrict__ bq, const float* __restrict__ bk, const float* __restrict__ bv,
    unsigned short* __restrict__ q, unsigned short* __restrict__ k, unsigned short* __restrict__ vt)
{
    __shared__ __align__(16) unsigned short As[128 * 64];   // 16 KB — shared by all
    __shared__ __align__(16) unsigned short Bs[128 * 64];   // 16 KB   three branches
    if (blockIdx.z == 0)
        gemm_body<3>(As, Bs, xb, wqb, bq, q,  blockIdx.x, blockIdx.y);
    else if (blockIdx.z == 1)
        gemm_body<1>(As, Bs, xb, wkb, bk, k,  blockIdx.x, blockIdx.y);
    else
        gemm_body<2>(As, Bs, xb, wvb, bv, vt, blockIdx.x, blockIdx.y);
}

// Kernel 4: output projection, fp32 out
__global__ __launch_bounds__(256) void out_gemm(
    const unsigned short* __restrict__ attn, const unsigned short* __restrict__ wob,
    const float* __restrict__ bo, float* __restrict__ out)
{
    __shared__ __align__(16) unsigned short As[128 * 64];
    __shared__ __align__(16) unsigned short Bs[128 * 64];
    gemm_body<0>(As, Bs, attn, wob, bo, out, blockIdx.x, blockIdx.y);
}

// ---------------------------------------------------------------------------
// Kernel 3: flash attention, P entirely in registers (no P-LDS, no shfl).
// Block = 4 waves / 64 Q-rows; wave-pairs split KV: pair 0 -> kv 0..1023,
// pair 1 -> kv 1024..2047 (16 iters each). Reduction-free softmax makes the
// pair-merge a pure add (O = O0+O1, l = l0+l1) done once via LDS at the end.
// QK^T: S^T = K·Q^T on 32x32x16 (C-layout: col=qrow=l31, kv per reg-quad).
// PV: 32x32x8 MFMA — A-frag k = 4*(lane>>5)+j matches exactly the 4 kv each
// lane owns per (mb,g) -> pack exp2(st) pairs and feed MFMA directly.
// V B-frags: ds_read_b64 from Vs [dh][kv] (16B-block XOR swizzle, +kq*8).
// Row-sum l via ones-MFMA (32x32x8). Grid (bh=32 fast -> XCD swizzle, qt=32).
// ---------------------------------------------------------------------------
__global__ __launch_bounds__(256) void attn_kernel(
    const unsigned short* __restrict__ q, const unsigned short* __restrict__ k,
    const unsigned short* __restrict__ vt, unsigned short* __restrict__ o)
{
    __shared__ __align__(16) unsigned short Ks[2][64 * 64];   // 16 KB, per-pair [kv][dh]
    __shared__ __align__(16) unsigned short Vs[2][64 * 64];   // 16 KB, per-pair [dh][kv]

    const int tid = threadIdx.x;
    const int lane = tid & 63, wave = tid >> 6;
    const int l31 = lane & 31, kq = lane >> 5;
    const int pair = wave >> 1, wrow = wave & 1;
    const int bh = blockIdx.x;        // b*H + h — FAST index: XCD = bh%8
    const int qt = blockIdx.y;        // Q tile (0..31), 64 rows
    const int b = bh >> 4, h = bh & 15;

    const unsigned short* qb = q  + (size_t)b * N_ * D_ + h * DH_;
    const unsigned short* kb = k  + (size_t)b * N_ * D_ + h * DH_;
    const unsigned short* vb = vt + (size_t)h * DH_ * BN_ + (size_t)b * N_;  // vt[h*64+dh][b*N+n]

    const int qrow0 = qt * 64 + wrow * 32;

    // Q B-frags (pre-scaled): lane l31 holds Q[qrow0+l31][s*16 + kq*8 .. +7]
    short8 qf[4];
#pragma unroll
    for (int s = 0; s < 4; s++)
        qf[s] = *(const short8*)(qb + (size_t)(qrow0 + l31) * D_ + s * 16 + kq * 8);

    f32x16 oacc[2] = {};   // O[qrow][dh], nb = dh-half (32x32 C-layout)
    f32x16 lacc = {};      // row-sums (all cols identical)

    short4v ones4;
#pragma unroll
    for (int j = 0; j < 4; j++) ones4[j] = (short)0x3F80;

    const int srow = lane >> 3, scb = lane & 7;
    const int kvbase = pair * (N_ / 2);

    for (int it = 0; it < N_ / 128; ++it) {   // 16 iters per pair
        const int kv0 = kvbase + it * 64;
        __syncthreads();   // all waves done reading previous tiles
#pragma unroll
        for (int cc = 0; cc < 4; ++cc) {       // 8 chunks per tile / 2 waves per pair
            int c  = wrow * 4 + cc;
            int lr = c * 8 + srow;             // 0..63
            int swz8 = (scb ^ (lr & 7)) * 8;
            async_load16(kb + (size_t)(kv0 + lr) * D_ + swz8, (unsigned short*)Ks[pair] + c * 512);
            async_load16(vb + (size_t)lr * BN_ + kv0 + swz8,  (unsigned short*)Vs[pair] + c * 512);
        }
        __syncthreads();   // staging complete

        const unsigned short* Kc = Ks[pair];
        const unsigned short* Vc = Vs[pair];

        // S^T = K·Q^T  (2 kv-halves x 4 dh-steps)
        f32x16 st[2] = {};
#pragma unroll
        for (int s = 0; s < 4; s++) {
#pragma unroll
            for (int mb = 0; mb < 2; mb++) {
                short8 kfr = *(const short8*)((const char*)Kc +
                    (mb * 32 + l31) * 128 + (((2 * s + kq) ^ (l31 & 7)) * 16));
                st[mb] = __builtin_amdgcn_mfma_f32_32x32x16_bf16(
                    kfr, qf[s], st[mb], 0, 0, 0);
            }
        }

        // exp2 + pack -> A-frag (registers), PV + row-sum via 32x32x8
#pragma unroll
        for (int mb = 0; mb < 2; mb++) {
#pragma unroll
            for (int g = 0; g < 4; g++) {
                float p0 = EXP2(st[mb][g * 4 + 0]);
                float p1 = EXP2(st[mb][g * 4 + 1]);
                float p2 = EXP2(st[mb][g * 4 + 2]);
                float p3 = EXP2(st[mb][g * 4 + 3]);
                uint2 val;
                val.x = pkbf(p0, p1);
                val.y = pkbf(p2, p3);
                short4v pf = __builtin_bit_cast(short4v, val);
                // lane's kv block: mb*32 + g*8 + kq*4 + {0..3} == k = 4*kq+j  ✓
#pragma unroll
                for (int nb = 0; nb < 2; nb++) {
                    short4v vf = *(const short4v*)((const char*)Vc +
                        (nb * 32 + l31) * 128 + (((mb * 4 + g) ^ (l31 & 7)) * 16) + kq * 8);
                    oacc[nb] = __builtin_amdgcn_mfma_f32_32x32x8bf16_1k(
                        pf, vf, oacc[nb], 0, 0, 0);
                }
                lacc = __builtin_amdgcn_mfma_f32_32x32x8bf16_1k(
                    pf, ones4, lacc, 0, 0, 0);
            }
        }
    }

    // -------- pair merge: O = O0+O1, l = l0+l1 (reduction-free softmax) -----
    // Reuse staging LDS: Ks region = oacc (128 lanes x 32 f32 = 16 KB),
    // Vs region = lacc (128 lanes x 16 f32 = 8 KB). Layout [slot][lane-idx]
    // -> lane-consecutive, conflict-free.
    float* MO = (float*)&Ks[0][0];
    float* ML = (float*)&Vs[0][0];
    const int idx = wrow * 64 + lane;   // 0..127 within the pair

    __syncthreads();   // everyone done with the last tiles
    if (pair == 1) {
#pragma unroll
        for (int s = 0; s < 16; s++) {
            MO[s * 128 + idx]        = oacc[0][s];
            MO[(16 + s) * 128 + idx] = oacc[1][s];
            ML[s * 128 + idx]        = lacc[s];
        }
    }
    __syncthreads();
    if (pair == 0) {
#pragma unroll
        for (int s = 0; s < 16; s++) {
            oacc[0][s] += MO[s * 128 + idx];
            oacc[1][s] += MO[(16 + s) * 128 + idx];
            lacc[s]    += ML[s * 128 + idx];
        }
        // epilogue: normalize by l, store bf16 attention output [B*N][D]
#pragma unroll
        for (int g = 0; g < 4; g++)
#pragma unroll
            for (int rr = 0; rr < 4; rr++) {
                int reg = g * 4 + rr;
                float inv = 1.f / lacc[reg];
                int row = qrow0 + rr + 8 * g + 4 * kq;
                size_t base = ((size_t)b * N_ + row) * D_ + h * DH_;
#pragma unroll
                for (int nb = 0; nb < 2; nb++)
                    o[base + nb * 32 + l31] = f2bf(oacc[nb][reg] * inv);
            }
    }
}

// ---------------------------------------------------------------------------
extern "C" void kernel_launch(void* const* d_in, const int* in_sizes, int n_in,
                              void* d_out, int out_size, void* d_ws, size_t ws_size,
                              hipStream_t stream)
{
    const float* x  = (const float*)d_in[0];
    const float* Wq = (const float*)d_in[1];
    const float* bq = (const float*)d_in[2];
    const float* Wk = (const float*)d_in[3];
    const float* bk = (const float*)d_in[4];
    const float* Wv = (const float*)d_in[5];
    const float* bv = (const float*)d_in[6];
    const float* Wo = (const float*)d_in[7];
    const float* bo = (const float*)d_in[8];
    float* out = (float*)d_out;

    char* ws = (char*)d_ws;
    unsigned short* xb  = (unsigned short*)(ws + 0);         //  8 MB  x bf16
    unsigned short* wqb = (unsigned short*)(ws + 8388608);   //  2 MB
    unsigned short* wkb = (unsigned short*)(ws + 10485760);  //  2 MB
    unsigned short* wvb = (unsigned short*)(ws + 12582912);  //  2 MB
    unsigned short* wob = (unsigned short*)(ws + 14680064);  //  2 MB
    unsigned short* qd  = (unsigned short*)(ws + 16777216);  //  8 MB  Q (pre-scaled)
    unsigned short* kd  = (unsigned short*)(ws + 25165824);  //  8 MB
    unsigned short* vtd = (unsigned short*)(ws + 33554432);  //  8 MB  V^T [D][B*N]
    unsigned short* ad  = (unsigned short*)(ws + 41943040);  //  8 MB  attn out
    // total 48 MB

    cast_kernel<<<8192, 256, 0, stream>>>(x, Wq, Wk, Wv, Wo, xb, wqb, wkb, wvb, wob);
    qkv_gemm<<<dim3(8, 32, 3), 256, 0, stream>>>(xb, wqb, wkb, wvb, bq, bk, bv, qd, kd, vtd);
    attn_kernel<<<dim3(32, 32), 256, 0, stream>>>(qd, kd, vtd, ad);
    out_gemm<<<dim3(8, 32), 256, 0, stream>>>(ad, wob, bo, out);
}

// Round 10
// 210.374 us; speedup vs baseline: 1.0304x; 1.0304x over previous
//
#include <hip/hip_runtime.h>
#include <hip/hip_bf16.h>

// Problem constants
#define B_  2
#define N_  2048
#define D_  1024
#define H_  16
#define DH_ 64
#define BN_ (B_*N_)   // 4096 rows total

typedef __attribute__((ext_vector_type(8))) short short8;    // 8 bf16 (K=16/32 A/B frag)
typedef __attribute__((ext_vector_type(4))) short short4v;   // 4 bf16 (K=8 A/B frag)
typedef __attribute__((ext_vector_type(4))) float f32x4;     // 16x16 C/D frag
typedef __attribute__((ext_vector_type(16))) float f32x16;   // 32x32 C/D frag

typedef __attribute__((address_space(3))) unsigned int lds_u32_t;
typedef const __attribute__((address_space(1))) unsigned int glb_u32_t;

// async global->LDS, 16B per lane; LDS dst = (wave-uniform base) + lane*16
__device__ __forceinline__ void async_load16(const unsigned short* g, unsigned short* l) {
    __builtin_amdgcn_global_load_lds((glb_u32_t*)g, (lds_u32_t*)l, 16, 0, 0);
}

__device__ __forceinline__ unsigned short f2bf(float f) {
    __hip_bfloat16 h = __float2bfloat16(f);
    return *reinterpret_cast<unsigned short*>(&h);
}

// pack bf16(a) low16 | bf16(b) high16; round-half-up + one v_perm_b32
__device__ __forceinline__ unsigned int pkbf(float a, float b) {
    unsigned int ua = __float_as_uint(a) + 0x8000u;
    unsigned int ub = __float_as_uint(b) + 0x8000u;
    return __builtin_amdgcn_perm(ub, ua, 0x07060302);
}

#if __has_builtin(__builtin_amdgcn_exp2f)
#define EXP2(x) __builtin_amdgcn_exp2f(x)
#else
#define EXP2(x) exp2f(x)
#endif

// softmax scale folded into Q projection: 1/sqrt(DH) * log2(e)
#define QSCL 0.1803368801111204f

// ---------------------------------------------------------------------------
// Kernel 1: cast fp32 -> bf16 for x, Wq, Wk, Wv, Wo (one fused launch)
// ---------------------------------------------------------------------------
__global__ __launch_bounds__(256) void cast_kernel(
    const float* __restrict__ x,  const float* __restrict__ wq,
    const float* __restrict__ wk, const float* __restrict__ wv,
    const float* __restrict__ wo,
    unsigned short* __restrict__ xb,  unsigned short* __restrict__ wqb,
    unsigned short* __restrict__ wkb, unsigned short* __restrict__ wvb,
    unsigned short* __restrict__ wob)
{
    const size_t NX = (size_t)BN_ * D_;   // 4194304
    const size_t NW = (size_t)D_ * D_;    // 1048576 (pow2)
    size_t i = ((size_t)blockIdx.x * 256 + threadIdx.x) * 4;
    const float* src; unsigned short* dst; size_t off;
    if (i < NX) { src = x; dst = xb; off = i; }
    else {
        size_t j = (i - NX) >> 20;          // which W
        off = (i - NX) & (NW - 1);
        src = (j == 0) ? wq : (j == 1) ? wk : (j == 2) ? wv : wo;
        dst = (j == 0) ? wqb : (j == 1) ? wkb : (j == 2) ? wvb : wob;
    }
    float4 v = *(const float4*)(src + off);
    ushort4 o;
    o.x = f2bf(v.x); o.y = f2bf(v.y); o.z = f2bf(v.z); o.w = f2bf(v.w);
    *(ushort4*)(dst + off) = o;
}

// ---------------------------------------------------------------------------
// GEMM body: C[M,Nc] = A[M,K](bf16) @ W[Nc,K]^T(bf16) + bias
// LDS buffers passed in (declared once at kernel scope — R8 fix).
// ---------------------------------------------------------------------------
template<int OUT_MODE>
__device__ __forceinline__ void gemm_body(
    unsigned short* __restrict__ As, unsigned short* __restrict__ Bs,
    const unsigned short* __restrict__ A, const unsigned short* __restrict__ W,
    const float* __restrict__ bias, void* __restrict__ Cout, int bx, int by)
{
    constexpr int K = D_;
    const int tid  = threadIdx.x;
    const int lane = tid & 63;
    const int wave = tid >> 6;
    const int wm = wave & 1, wn = wave >> 1;
    const int l15 = lane & 15, quad = lane >> 4;

    f32x4 acc[4][4] = {};
    const int row0 = by * 128, col0 = bx * 128;

    const int srow = lane >> 3;   // row within 1KB chunk (8 rows x 128B)
    const int scb  = lane & 7;    // 16B block within row

    for (int k0 = 0; k0 < K; k0 += 64) {
        __syncthreads();
#pragma unroll
        for (int cc = 0; cc < 4; ++cc) {       // 16 chunks / 4 waves
            int c  = wave * 4 + cc;
            int lr = c * 8 + srow;             // tile row 0..127
            int gcol = k0 + ((scb ^ (lr & 7)) * 8);
            async_load16(A + (size_t)(row0 + lr) * K + gcol, As + c * 512);
            async_load16(W + (size_t)(col0 + lr) * K + gcol, Bs + c * 512);
        }
        __syncthreads();

#pragma unroll
        for (int kf = 0; kf < 2; ++kf) {
            const int swz = ((kf * 4 + quad) ^ (l15 & 7)) * 8;
            short8 af[4], bf[4];
#pragma unroll
            for (int mi = 0; mi < 4; mi++)
                af[mi] = *(const short8*)(&As[(wm * 64 + mi * 16 + l15) * 64 + swz]);
#pragma unroll
            for (int ni = 0; ni < 4; ni++)
                bf[ni] = *(const short8*)(&Bs[(wn * 64 + ni * 16 + l15) * 64 + swz]);
#pragma unroll
            for (int mi = 0; mi < 4; mi++)
#pragma unroll
                for (int ni = 0; ni < 4; ni++)
                    acc[mi][ni] = __builtin_amdgcn_mfma_f32_16x16x32_bf16(
                        af[mi], bf[ni], acc[mi][ni], 0, 0, 0);
        }
    }

#pragma unroll
    for (int ni = 0; ni < 4; ni++) {
        int col = col0 + wn * 64 + ni * 16 + l15;
        float bv = bias[col];
#pragma unroll
        for (int mi = 0; mi < 4; mi++) {
            int row = row0 + wm * 64 + mi * 16 + quad * 4;
            if (OUT_MODE == 2) {
                ushort4 pk;
                pk.x = f2bf(acc[mi][ni][0] + bv);
                pk.y = f2bf(acc[mi][ni][1] + bv);
                pk.z = f2bf(acc[mi][ni][2] + bv);
                pk.w = f2bf(acc[mi][ni][3] + bv);
                *(ushort4*)((unsigned short*)Cout + (size_t)col * BN_ + row) = pk;
            } else {
#pragma unroll
                for (int r = 0; r < 4; r++) {
                    float v = acc[mi][ni][r] + bv;
                    if (OUT_MODE == 3) v *= QSCL;
                    if (OUT_MODE == 0)
                        ((float*)Cout)[(size_t)(row + r) * D_ + col] = v;
                    else
                        ((unsigned short*)Cout)[(size_t)(row + r) * D_ + col] = f2bf(v);
                }
            }
        }
    }
}

// Kernel 2: fused QKV projection (z selects q/k/v; q pre-scaled, v transposed)
__global__ __launch_bounds__(256) void qkv_gemm(
    const unsigned short* __restrict__ xb,
    const unsigned short* __restrict__ wqb, const unsigned short* __restrict__ wkb,
    const unsigned short* __restrict__ wvb,
    const float* __restrict__ bq, const float* __restrict__ bk, const float* __restrict__ bv,
    unsigned short* __restrict__ q, unsigned short* __restrict__ k, unsigned short* __restrict__ vt)
{
    __shared__ __align__(16) unsigned short As[128 * 64];   // 16 KB — shared by all
    __shared__ __align__(16) unsigned short Bs[128 * 64];   // 16 KB   three branches
    if (blockIdx.z == 0)
        gemm_body<3>(As, Bs, xb, wqb, bq, q,  blockIdx.x, blockIdx.y);
    else if (blockIdx.z == 1)
        gemm_body<1>(As, Bs, xb, wkb, bk, k,  blockIdx.x, blockIdx.y);
    else
        gemm_body<2>(As, Bs, xb, wvb, bv, vt, blockIdx.x, blockIdx.y);
}

// Kernel 4: output projection, fp32 out
__global__ __launch_bounds__(256) void out_gemm(
    const unsigned short* __restrict__ attn, const unsigned short* __restrict__ wob,
    const float* __restrict__ bo, float* __restrict__ out)
{
    __shared__ __align__(16) unsigned short As[128 * 64];
    __shared__ __align__(16) unsigned short Bs[128 * 64];
    gemm_body<0>(As, Bs, attn, wob, bo, out, blockIdx.x, blockIdx.y);
}

// ---------------------------------------------------------------------------
// Kernel 3: flash attention — R8 shape (128 Q-rows/block, 4 waves, full KV)
// + register-P PV (32x32x8bf16_1k, layout proven in R9) + VALU row-sum +
// double-buffered K/V staging with ONE barrier per iteration.
//   S^T = K·Q^T on 32x32x16: C-layout col = qrow = l31, kv per reg-quad
//   (kv = 32mb + 8g + 4kq + rr) — exactly the 32x32x8 A-frag k = 4kq+j.
//   l[qrow=l31] accumulates in VALU across the whole loop; one shfl_xor(32)
//   + tiny per-wave LDS table re-indexes it to the C-layout epilogue.
//   Dbuf: prefetch tile i+1 right after the barrier that opens compute on
//   tile i; next barrier's vmcnt drain then finds the loads already landed.
// LDS 32 KB, no P array, no lgkm drain in the hot loop, no P bank conflicts.
// ---------------------------------------------------------------------------
__global__ __launch_bounds__(256) void attn_kernel(
    const unsigned short* __restrict__ q, const unsigned short* __restrict__ k,
    const unsigned short* __restrict__ vt, unsigned short* __restrict__ o)
{
    __shared__ __align__(16) unsigned short Ks[2][64 * 64];   // 16 KB dbuf [kv][dh]
    __shared__ __align__(16) unsigned short Vs[2][64 * 64];   // 16 KB dbuf [dh][kv]

    const int tid = threadIdx.x;
    const int lane = tid & 63, wave = tid >> 6;
    const int l31 = lane & 31, kq = lane >> 5;
    const int bh = blockIdx.x;        // b*H + h — FAST index: XCD = bh%8
    const int qt = blockIdx.y;        // Q tile (0..15), 128 rows
    const int b = bh >> 4, h = bh & 15;

    const unsigned short* qb = q  + (size_t)b * N_ * D_ + h * DH_;
    const unsigned short* kb = k  + (size_t)b * N_ * D_ + h * DH_;
    const unsigned short* vb = vt + (size_t)h * DH_ * BN_ + (size_t)b * N_;  // vt[h*64+dh][b*N+n]

    const int qrow0 = qt * 128 + wave * 32;

    // Q B-frags (pre-scaled): lane l31 holds Q[qrow0+l31][s*16 + kq*8 .. +7]
    short8 qf[4];
#pragma unroll
    for (int s = 0; s < 4; s++)
        qf[s] = *(const short8*)(qb + (size_t)(qrow0 + l31) * D_ + s * 16 + kq * 8);

    f32x16 oacc[2] = {};   // O[qrow][dh] (32x32 C-layout), nb = dh-half
    float lsum = 0.f;      // running row-sum for qrow = l31 (this lane's kv share)

    const int srow = lane >> 3, scb = lane & 7;

    // stage K/V tile kv0 into buffer bi (2 async chunks each per wave)
    auto stage = [&](int bi, int kv0) {
#pragma unroll
        for (int cc = 0; cc < 2; ++cc) {
            int c  = wave * 2 + cc;
            int lr = c * 8 + srow;             // 0..63
            int swz8 = (scb ^ (lr & 7)) * 8;
            async_load16(kb + (size_t)(kv0 + lr) * D_ + swz8, (unsigned short*)Ks[bi] + c * 512);
            async_load16(vb + (size_t)lr * BN_ + kv0 + swz8,  (unsigned short*)Vs[bi] + c * 512);
        }
    };

    stage(0, 0);   // prologue

    const int NIT = N_ / 64;   // 32
    for (int it = 0; it < NIT; ++it) {
        const int cur = it & 1;
        __syncthreads();   // drains vmcnt -> buf[cur] ready; buf[cur^1] readers done
        if (it + 1 < NIT) stage(cur ^ 1, (it + 1) * 64);   // prefetch next tile

        const unsigned short* Kc = Ks[cur];
        const unsigned short* Vc = Vs[cur];

        // S^T = K·Q^T  (2 kv-halves x 4 dh-steps)
        f32x16 st[2] = {};
#pragma unroll
        for (int s = 0; s < 4; s++) {
#pragma unroll
            for (int mb = 0; mb < 2; mb++) {
                short8 kfr = *(const short8*)((const char*)Kc +
                    (mb * 32 + l31) * 128 + (((2 * s + kq) ^ (l31 & 7)) * 16));
                st[mb] = __builtin_amdgcn_mfma_f32_32x32x16_bf16(
                    kfr, qf[s], st[mb], 0, 0, 0);
            }
        }

        // exp2 + pack -> register A-frag; PV via 32x32x8; row-sum in VALU
#pragma unroll
        for (int mb = 0; mb < 2; mb++) {
#pragma unroll
            for (int g = 0; g < 4; g++) {
                float p0 = EXP2(st[mb][g * 4 + 0]);
                float p1 = EXP2(st[mb][g * 4 + 1]);
                float p2 = EXP2(st[mb][g * 4 + 2]);
                float p3 = EXP2(st[mb][g * 4 + 3]);
                lsum += (p0 + p1) + (p2 + p3);
                uint2 val;
                val.x = pkbf(p0, p1);
                val.y = pkbf(p2, p3);
                short4v pf = __builtin_bit_cast(short4v, val);
                // lane's kv block: 32mb + 8g + 4kq + {0..3} == A-frag k = 4kq+j
#pragma unroll
                for (int nb = 0; nb < 2; nb++) {
                    short4v vf = *(const short4v*)((const char*)Vc +
                        (nb * 32 + l31) * 128 + (((mb * 4 + g) ^ (l31 & 7)) * 16) + kq * 8);
                    oacc[nb] = __builtin_amdgcn_mfma_f32_32x32x8bf16_1k(
                        pf, vf, oacc[nb], 0, 0, 0);
                }
            }
        }
    }

    // ---- finalize l: combine kq halves, re-index l31-space -> reg-space ----
    lsum += __shfl_xor(lsum, 32);          // now lsum = l[qrow = qrow0 + l31]
    __syncthreads();                       // all tile reads done; Ks reusable
    float* Lt = (float*)&Ks[0][0] + wave * 32;   // per-wave 128B table
    if (kq == 0) Lt[l31] = lsum;
    asm volatile("s_waitcnt lgkmcnt(0)" ::: "memory");

    // epilogue: normalize by l, store bf16 attention output [B*N][D]
#pragma unroll
    for (int g = 0; g < 4; g++)
#pragma unroll
        for (int rr = 0; rr < 4; rr++) {
            int reg = g * 4 + rr;
            float inv = 1.f / Lt[rr + 8 * g + 4 * kq];   // wave-uniform per kq: broadcast
            int row = qrow0 + rr + 8 * g + 4 * kq;
            size_t base = ((size_t)b * N_ + row) * D_ + h * DH_;
#pragma unroll
            for (int nb = 0; nb < 2; nb++)
                o[base + nb * 32 + l31] = f2bf(oacc[nb][reg] * inv);
        }
}

// ---------------------------------------------------------------------------
extern "C" void kernel_launch(void* const* d_in, const int* in_sizes, int n_in,
                              void* d_out, int out_size, void* d_ws, size_t ws_size,
                              hipStream_t stream)
{
    const float* x  = (const float*)d_in[0];
    const float* Wq = (const float*)d_in[1];
    const float* bq = (const float*)d_in[2];
    const float* Wk = (const float*)d_in[3];
    const float* bk = (const float*)d_in[4];
    const float* Wv = (const float*)d_in[5];
    const float* bv = (const float*)d_in[6];
    const float* Wo = (const float*)d_in[7];
    const float* bo = (const float*)d_in[8];
    float* out = (float*)d_out;

    char* ws = (char*)d_ws;
    unsigned short* xb  = (unsigned short*)(ws + 0);         //  8 MB  x bf16
    unsigned short* wqb = (unsigned short*)(ws + 8388608);   //  2 MB
    unsigned short* wkb = (unsigned short*)(ws + 10485760);  //  2 MB
    unsigned short* wvb = (unsigned short*)(ws + 12582912);  //  2 MB
    unsigned short* wob = (unsigned short*)(ws + 14680064);  //  2 MB
    unsigned short* qd  = (unsigned short*)(ws + 16777216);  //  8 MB  Q (pre-scaled)
    unsigned short* kd  = (unsigned short*)(ws + 25165824);  //  8 MB
    unsigned short* vtd = (unsigned short*)(ws + 33554432);  //  8 MB  V^T [D][B*N]
    unsigned short* ad  = (unsigned short*)(ws + 41943040);  //  8 MB  attn out
    // total 48 MB

    cast_kernel<<<8192, 256, 0, stream>>>(x, Wq, Wk, Wv, Wo, xb, wqb, wkb, wvb, wob);
    qkv_gemm<<<dim3(8, 32, 3), 256, 0, stream>>>(xb, wqb, wkb, wvb, bq, bk, bv, qd, kd, vtd);
    attn_kernel<<<dim3(32, 16), 256, 0, stream>>>(qd, kd, vtd, ad);
    out_gemm<<<dim3(8, 32), 256, 0, stream>>>(ad, wob, bo, out);
}